// Round 10
// baseline (254.594 us; speedup 1.0000x reference)
//
#include <hip/hip_runtime.h>
#include <hip/hip_fp16.h>

// GCN tail: 2×(GCNConv+ReLU) + linear head.  N=100000, E=1000000, F_in=128, H=64, C=40.
//
// R10: fusion round — pipeline is 6 dispatches:
//   zero -> bucket_fill(1024 edges/blk, 977 blks) -> node_sort(512 thr)
//   -> gemm_tiled (x@W1, *dinv, fp16)
//   -> gather_gemm  (gather+b1+relu -> LDS rows -> @W2 -> *dinv -> fp16 bufC)
//   -> gather_head  (gather+b2+relu -> LDS rows -> @Wc + bc -> fp32 d_out)
// Kills 2 launches + two 12.8 MB intermediate round-trips + GEMM A-staging.
// R9 evidence: no single hot kernel left (top-5 = 41 us harness poison only);
// remaining time is spread over 11 dispatches + low-parallelism build
// (bucket_fill was 245 blocks = 1/CU).

#define BUCKET_BITS  8
#define BUCKET_NODES 256
#define MAXB 512            // max buckets supported (N <= 131072)
#define CAP  8192           // slots per bucket window (Binom(1M,1/391)=2558±51)
#define OFF_MASK 0x3FFFFF   // 22 bits
#define EPB  1024           // edges per bucket_fill block

union H8 { uint4 u; __half h[8]; };
union H4 { uint2 u; __half h[4]; };

__global__ void zero_kernel(int* __restrict__ p, int n) {
    int i = blockIdx.x * blockDim.x + threadIdx.x;
    if (i < n) p[i] = 0;
}

// Single-pass counting-sort fill into fixed-capacity bucket windows.
// entry = (dstLocal<<24) | src   (src < 2^24).  1024 edges/block -> 977 blocks.
__global__ __launch_bounds__(256) void bucket_fill_kernel(const int* __restrict__ src,
                                                          const int* __restrict__ dst,
                                                          int* __restrict__ bucketCursor,
                                                          unsigned int* __restrict__ bucketArr,
                                                          int E, int NB) {
    __shared__ int lcnt[MAXB];
    __shared__ int dcache[EPB];
    for (int i = threadIdx.x; i < NB; i += 256) lcnt[i] = 0;
    __syncthreads();
    const int base = blockIdx.x * EPB;
#pragma unroll
    for (int k = 0; k < EPB / 256; ++k) {
        int idx = k * 256 + threadIdx.x;
        int e = base + idx;
        if (e < E) {
            int d = dst[e];
            dcache[idx] = d;
            atomicAdd(&lcnt[d >> BUCKET_BITS], 1);
        }
    }
    __syncthreads();
    for (int i = threadIdx.x; i < NB; i += 256) {
        int c = lcnt[i];
        if (c) lcnt[i] = i * CAP + atomicAdd(&bucketCursor[i], c);  // count -> abs base
    }
    __syncthreads();
#pragma unroll
    for (int k = 0; k < EPB / 256; ++k) {
        int idx = k * 256 + threadIdx.x;
        int e = base + idx;
        if (e < E) {
            int d = dcache[idx];
            int s = src[e];
            int pos = atomicAdd(&lcnt[d >> BUCKET_BITS], 1);
            bucketArr[pos] = ((unsigned)(d & (BUCKET_NODES - 1)) << 24) | (unsigned)s;
        }
    }
}

// Per bucket (512 threads): count -> scan -> nodeInfo=(cnt<<22)|absOff + dinv,
// then scatter src-only adj entries via LDS cursors (window L2-hot).
__global__ __launch_bounds__(512) void node_sort_kernel(const unsigned int* __restrict__ bucketArr,
                                                        const int* __restrict__ bucketCursor,
                                                        unsigned int* __restrict__ nodeInfo,
                                                        float* __restrict__ dinv,
                                                        unsigned int* __restrict__ adj, int N) {
    __shared__ int cnt[BUCKET_NODES];
    __shared__ int scn[BUCKET_NODES];
    __shared__ int cur[BUCKET_NODES];
    const int t = threadIdx.x;
    const int b = blockIdx.x;
    if (t < BUCKET_NODES) cnt[t] = 0;
    __syncthreads();
    const int e0 = b * CAP;
    const int e1 = e0 + bucketCursor[b];
    for (int e = e0 + t; e < e1; e += 512)
        atomicAdd(&cnt[bucketArr[e] >> 24], 1);
    __syncthreads();
    int v = 0;
    if (t < BUCKET_NODES) { v = cnt[t]; scn[t] = v; }
    __syncthreads();
    for (int off = 1; off < BUCKET_NODES; off <<= 1) {
        int u = (t < BUCKET_NODES && t >= off) ? scn[t - off] : 0;
        __syncthreads();
        if (t < BUCKET_NODES) scn[t] += u;
        __syncthreads();
    }
    if (t < BUCKET_NODES) {
        const int excl = scn[t] - v;
        const int node = b * BUCKET_NODES + t;
        if (node < N) {
            nodeInfo[node] = ((unsigned)v << 22) | (unsigned)(e0 + excl);
            dinv[node]     = rsqrtf((float)(v + 1));
        }
        cur[t] = e0 + excl;
    }
    __syncthreads();
    for (int e = e0 + t; e < e1; e += 512) {
        unsigned int entry = bucketArr[e];
        int pos = atomicAdd(&cur[entry >> 24], 1);
        adj[pos] = entry & 0xFFFFFF;
    }
}

// ---- LDS-tiled GEMM (layer 1 only): out = (A @ W) * dinv[row], fp16 --------
template <int K, int NOUT>
__global__ __launch_bounds__(256) void gemm_tiled(const float* __restrict__ A,
                                                  const float* __restrict__ W,
                                                  const float* __restrict__ dscale,
                                                  __half* __restrict__ outv, int M) {
    constexpr int KS  = 64;
    constexpr int NST = K / KS;
    __shared__ float At[64 * 66];
    __shared__ float Wt[K * 64];

    for (int i = threadIdx.x; i < K * 64; i += 256) Wt[i] = W[i];

    const int tc   = threadIdx.x & 15;
    const int tr   = threadIdx.x >> 4;
    const int row0 = blockIdx.x * 64;

    float acc[4][4] = {};

    for (int st = 0; st < NST; ++st) {
        __syncthreads();
        int g = threadIdx.x;
#pragma unroll
        for (int i = 0; i < 4; ++i, g += 256) {
            int r  = g >> 4;
            int kc = (g & 15) << 2;
            int grow = row0 + r;
            if (grow > M - 1) grow = M - 1;
            float4 v = *(const float4*)(A + (size_t)grow * K + st * KS + kc);
            float* p = &At[r * 66 + kc];
            p[0] = v.x; p[1] = v.y; p[2] = v.z; p[3] = v.w;
        }
        __syncthreads();

        const float* a0p = &At[(tr * 4 + 0) * 66];
        const float* a1p = &At[(tr * 4 + 1) * 66];
        const float* a2p = &At[(tr * 4 + 2) * 66];
        const float* a3p = &At[(tr * 4 + 3) * 66];
        const float* wp  = &Wt[st * KS * 64 + tc * 4];
#pragma unroll 8
        for (int k = 0; k < KS; ++k) {
            float a0 = a0p[k];
            float a1 = a1p[k];
            float a2 = a2p[k];
            float a3 = a3p[k];
            float4 w = *(const float4*)(wp + k * 64);
            acc[0][0] += a0 * w.x; acc[0][1] += a0 * w.y; acc[0][2] += a0 * w.z; acc[0][3] += a0 * w.w;
            acc[1][0] += a1 * w.x; acc[1][1] += a1 * w.y; acc[1][2] += a1 * w.z; acc[1][3] += a1 * w.w;
            acc[2][0] += a2 * w.x; acc[2][1] += a2 * w.y; acc[2][2] += a2 * w.z; acc[2][3] += a2 * w.w;
            acc[3][0] += a3 * w.x; acc[3][1] += a3 * w.y; acc[3][2] += a3 * w.z; acc[3][3] += a3 * w.w;
        }
    }

#pragma unroll
    for (int j = 0; j < 4; ++j) {
        int row = row0 + tr * 4 + j;
        if (row >= M) break;
        float sc = dscale[row];
        H4 v;
        v.h[0] = __float2half(acc[j][0] * sc);
        v.h[1] = __float2half(acc[j][1] * sc);
        v.h[2] = __float2half(acc[j][2] * sc);
        v.h[3] = __float2half(acc[j][3] * sc);
        *(uint2*)(outv + (size_t)row * NOUT + tc * 4) = v.u;
    }
}

// Fused gather + GEMM2.  32 nodes/block, 256 threads.
// Phase 1 (eighth-wave gather): acc = h'[node] + sum_s h'[s]; row = relu(acc*di+b1)
// Phase 2: LDS rows (32x72) @ LDS W2 (64x64) -> *dinv -> fp16 out.
__global__ __launch_bounds__(256) void gather_gemm_kernel(const __half* __restrict__ h,
                                                          const unsigned int* __restrict__ nodeInfo,
                                                          const unsigned int* __restrict__ adj,
                                                          const float* __restrict__ dinv,
                                                          const float* __restrict__ bias,
                                                          const float* __restrict__ W,   // 64x64
                                                          __half* __restrict__ out, int N) {
    __shared__ float rows[32 * 72];
    __shared__ float Wt[64 * 64];
    for (int i = threadIdx.x; i < 64 * 64; i += 256) Wt[i] = W[i];

    const int nodeRaw = blockIdx.x * 32 + (threadIdx.x >> 3);
    const int node = min(nodeRaw, N - 1);
    const int o    = (threadIdx.x >> 3) & 7;
    const int l    = threadIdx.x & 7;
    const int ln   = threadIdx.x >> 3;

    const unsigned info = nodeInfo[node];
    const int start = (int)(info & OFF_MASK);
    const int end   = start + (int)(info >> 22);
    const float di  = dinv[node];

    float acc[8];
    {
        H8 sv;
        sv.u = *(const uint4*)(h + (size_t)node * 64 + l * 8);
#pragma unroll
        for (int k = 0; k < 8; ++k) acc[k] = __half2float(sv.h[k]);
    }
    for (int base = start; ; base += 8) {
        bool active = base < end;
        if (__ballot(active) == 0ull) break;
        int m = 0, sidx = 0;
        if (active) {
            m = min(8, end - base);
            if (l < m) sidx = (int)adj[base + l];
        }
#pragma unroll
        for (int j = 0; j < 8; ++j) {
            if (j < m) {
                int s = __shfl(sidx, (o << 3) | j);
                H8 rv;
                rv.u = *(const uint4*)(h + (size_t)s * 64 + l * 8);
#pragma unroll
                for (int k = 0; k < 8; ++k) acc[k] += __half2float(rv.h[k]);
            }
        }
    }
    {
        const float4 b0 = *(const float4*)(bias + l * 8);
        const float4 b1 = *(const float4*)(bias + l * 8 + 4);
        const float bb[8] = {b0.x, b0.y, b0.z, b0.w, b1.x, b1.y, b1.z, b1.w};
        float* rp = &rows[ln * 72 + l * 8];
#pragma unroll
        for (int k = 0; k < 8; ++k) {
            float v = acc[k] * di + bb[k];
            rp[k] = v > 0.f ? v : 0.f;
        }
    }
    __syncthreads();

    // GEMM: thread (ln, cg=l) computes cols l*8..+7 for node ln.
    float o8[8] = {};
    const float* rp = &rows[ln * 72];
#pragma unroll 8
    for (int k = 0; k < 64; ++k) {
        float a = rp[k];
        float4 w0 = *(const float4*)(&Wt[k * 64 + l * 8]);
        float4 w1 = *(const float4*)(&Wt[k * 64 + l * 8 + 4]);
        o8[0] += a * w0.x; o8[1] += a * w0.y; o8[2] += a * w0.z; o8[3] += a * w0.w;
        o8[4] += a * w1.x; o8[5] += a * w1.y; o8[6] += a * w1.z; o8[7] += a * w1.w;
    }
    if (nodeRaw < N) {
        H8 ov;
#pragma unroll
        for (int k = 0; k < 8; ++k) ov.h[k] = __float2half(o8[k] * di);
        *(uint4*)(out + (size_t)node * 64 + l * 8) = ov.u;
    }
}

// Fused gather + head.  Phase 1 as above (bias=b2); Phase 2: rows @ Wc(64x40)
// + bc -> fp32 d_out.
__global__ __launch_bounds__(256) void gather_head_kernel(const __half* __restrict__ h,
                                                          const unsigned int* __restrict__ nodeInfo,
                                                          const unsigned int* __restrict__ adj,
                                                          const float* __restrict__ dinv,
                                                          const float* __restrict__ bias,
                                                          const float* __restrict__ W,   // 64x40
                                                          const float* __restrict__ bout,
                                                          float* __restrict__ out, int N) {
    __shared__ float rows[32 * 72];
    __shared__ float Wt[64 * 40];
    for (int i = threadIdx.x; i < 64 * 40; i += 256) Wt[i] = W[i];

    const int nodeRaw = blockIdx.x * 32 + (threadIdx.x >> 3);
    const int node = min(nodeRaw, N - 1);
    const int o    = (threadIdx.x >> 3) & 7;
    const int l    = threadIdx.x & 7;
    const int ln   = threadIdx.x >> 3;

    const unsigned info = nodeInfo[node];
    const int start = (int)(info & OFF_MASK);
    const int end   = start + (int)(info >> 22);
    const float di  = dinv[node];

    float acc[8];
    {
        H8 sv;
        sv.u = *(const uint4*)(h + (size_t)node * 64 + l * 8);
#pragma unroll
        for (int k = 0; k < 8; ++k) acc[k] = __half2float(sv.h[k]);
    }
    for (int base = start; ; base += 8) {
        bool active = base < end;
        if (__ballot(active) == 0ull) break;
        int m = 0, sidx = 0;
        if (active) {
            m = min(8, end - base);
            if (l < m) sidx = (int)adj[base + l];
        }
#pragma unroll
        for (int j = 0; j < 8; ++j) {
            if (j < m) {
                int s = __shfl(sidx, (o << 3) | j);
                H8 rv;
                rv.u = *(const uint4*)(h + (size_t)s * 64 + l * 8);
#pragma unroll
                for (int k = 0; k < 8; ++k) acc[k] += __half2float(rv.h[k]);
            }
        }
    }
    {
        const float4 b0 = *(const float4*)(bias + l * 8);
        const float4 b1 = *(const float4*)(bias + l * 8 + 4);
        const float bb[8] = {b0.x, b0.y, b0.z, b0.w, b1.x, b1.y, b1.z, b1.w};
        float* rp = &rows[ln * 72 + l * 8];
#pragma unroll
        for (int k = 0; k < 8; ++k) {
            float v = acc[k] * di + bb[k];
            rp[k] = v > 0.f ? v : 0.f;
        }
    }
    __syncthreads();

    // Head: thread (ln, cg=l) computes cols l*5..+4 for node ln.
    float o5[5] = {};
    const float* rp = &rows[ln * 72];
#pragma unroll 4
    for (int k = 0; k < 64; ++k) {
        float a = rp[k];
        const float* wk = &Wt[k * 40 + l * 5];
        o5[0] += a * wk[0];
        o5[1] += a * wk[1];
        o5[2] += a * wk[2];
        o5[3] += a * wk[3];
        o5[4] += a * wk[4];
    }
    if (nodeRaw < N) {
        float* op = out + (size_t)node * 40 + l * 5;
        const float* bp = bout + l * 5;
#pragma unroll
        for (int j = 0; j < 5; ++j) op[j] = o5[j] + bp[j];
    }
}

extern "C" void kernel_launch(void* const* d_in, const int* in_sizes, int n_in,
                              void* d_out, int out_size, void* d_ws, size_t ws_size,
                              hipStream_t stream) {
    const float* x  = (const float*)d_in[0];
    const int*   ei = (const int*)d_in[1];
    const float* W1 = (const float*)d_in[2];
    const float* b1 = (const float*)d_in[3];
    const float* W2 = (const float*)d_in[4];
    const float* b2 = (const float*)d_in[5];
    const float* Wc = (const float*)d_in[6];
    const float* bc = (const float*)d_in[7];

    const int N = in_sizes[0] / 128;   // 100000
    const int E = in_sizes[1] / 2;     // 1000000
    const int* src = ei;
    const int* dst = ei + E;

    const int NB = (N + BUCKET_NODES - 1) >> BUCKET_BITS;   // 391
    const int EB = (E + EPB - 1) / EPB;                      // 977

    char* w = (char*)d_ws;
    auto alloc = [&](size_t bytes) { char* p = w; w += (bytes + 255) & ~(size_t)255; return p; };
    int*          bucketCursor = (int*)alloc((size_t)NB * 4);
    unsigned int* bucketArr    = (unsigned int*)alloc((size_t)NB * CAP * 4);
    unsigned int* nodeInfo     = (unsigned int*)alloc((size_t)N * 4);
    unsigned int* adj          = (unsigned int*)alloc((size_t)NB * CAP * 4);
    float*        dinv         = (float*)alloc((size_t)N * 4);
    __half*       bufA         = (__half*)alloc((size_t)N * 64 * 2);
    __half*       bufC         = (__half*)alloc((size_t)N * 64 * 2);

    dim3 blk(256);
    const int nblkG = (N + 63) / 64;
    const int nblkF = (N + 31) / 32;   // fused gather blocks: 32 nodes each

    // ---- bucket build (3 launches) ----
    zero_kernel<<<(NB + 255) / 256, blk, 0, stream>>>(bucketCursor, NB);
    bucket_fill_kernel<<<EB, blk, 0, stream>>>(src, dst, bucketCursor, bucketArr, E, NB);
    node_sort_kernel<<<NB, 512, 0, stream>>>(bucketArr, bucketCursor, nodeInfo, dinv, adj, N);

    // ---- layer 1 GEMM:  bufA = (x @ W1) * dinv[row] ----
    gemm_tiled<128, 64><<<nblkG, blk, 0, stream>>>(x, W1, dinv, bufA, N);

    // ---- fused gather+GEMM2:  bufC = (relu(gather(bufA)+b1) @ W2) * dinv ----
    gather_gemm_kernel<<<nblkF, blk, 0, stream>>>(bufA, nodeInfo, adj, dinv, b1, W2, bufC, N);

    // ---- fused gather+head:  d_out = relu(gather(bufC)+b2) @ Wc + bc ----
    gather_head_kernel<<<nblkF, blk, 0, stream>>>(bufC, nodeInfo, adj, dinv, b2, Wc, bc, (float*)d_out, N);
}